// Round 2
// 288.800 us; speedup vs baseline: 1.0200x; 1.0200x over previous
//
#include <hip/hip_runtime.h>

#define NN 2048
#define BB 8
#define TROW 128928   // sum_{d=1..64} (2047-d)

typedef __attribute__((ext_vector_type(8))) short bf16x8;
typedef __attribute__((ext_vector_type(4))) float f32x4;

__device__ __forceinline__ short f2bf(float f) {
    unsigned u = __float_as_uint(f);
    unsigned r = (u + 0x7FFFu + ((u >> 16) & 1u)) >> 16;   // RNE
    return (short)r;
}

// ---------------- k_stage1: fused left(MFMA, full-K) + right(column-sum partials) ------------
// blocks 0..255: R = X(16384x2048) . wl^T(2048x15) via MFMA, FULL K per wave (64 iters)
//   -> writes R directly, no k-split partials, no reduction kernel needed.
//   grid-part 256 = 8 b x 32 rowgroups(64); wave = 16 rows.
//   A-frag: lane(q,m) holds x[r0+m][q*8+it*32+j]; B-frag from wl row m (15 clamped);
//   D col(lane&15)=channel, row(q*4+reg)=x-row  [m89 C/D mapping].
// blocks 256..511: CSp[rc][b][k][j] partial column sums; thread owns 4 cols, 128 rows;
//   weights read via block-uniform scalar loads (s_load, L2-hot).
//   NOTE: x (134 MB) fits the 256 MiB L3, so this second pass over x is largely
//   Infinity-Cache-fed while the MFMA pass streams from HBM.
// block 0 zeroes psum[64] + counters[2].
__global__ __launch_bounds__(256) void k_stage1(const float* __restrict__ x,
                                                const float* __restrict__ wl,
                                                const float* __restrict__ wr,
                                                float* __restrict__ R,
                                                float* __restrict__ CSp,
                                                float* __restrict__ psum,
                                                int* __restrict__ counters) {
    int blk = blockIdx.x;
    int tid = threadIdx.x;
    if (blk == 0) {
        if (tid < 64) psum[tid] = 0.f;
        else if (tid < 66) counters[tid - 64] = 0;
    }
    if (blk < 256) {
        // ---- MFMA row-dot path, full K ----
        int b = blk >> 5;
        int rg = blk & 31;
        int wv = tid >> 6, lane = tid & 63;
        int q = lane >> 4, m = lane & 15;
        int r0 = rg * 64 + wv * 16;
        int nrow = (m == 15) ? 14 : m;

        const float* ap = x + ((size_t)(b * NN + r0 + m)) * NN + q * 8;
        const float* bp = wl + (size_t)nrow * NN + q * 8;

        f32x4 acc = {0.f, 0.f, 0.f, 0.f};
#pragma unroll 4
        for (int it = 0; it < 64; it++) {
            const float* a0 = ap + it * 32;
            const float* b0 = bp + it * 32;
            float4 av0 = *(const float4*)(a0);
            float4 av1 = *(const float4*)(a0 + 4);
            float4 bv0 = *(const float4*)(b0);
            float4 bv1 = *(const float4*)(b0 + 4);
            bf16x8 af, bf;
            af[0] = f2bf(av0.x); af[1] = f2bf(av0.y); af[2] = f2bf(av0.z); af[3] = f2bf(av0.w);
            af[4] = f2bf(av1.x); af[5] = f2bf(av1.y); af[6] = f2bf(av1.z); af[7] = f2bf(av1.w);
            bf[0] = f2bf(bv0.x); bf[1] = f2bf(bv0.y); bf[2] = f2bf(bv0.z); bf[3] = f2bf(bv0.w);
            bf[4] = f2bf(bv1.x); bf[5] = f2bf(bv1.y); bf[6] = f2bf(bv1.z); bf[7] = f2bf(bv1.w);
            acc = __builtin_amdgcn_mfma_f32_16x16x32_bf16(af, bf, acc, 0, 0, 0);
        }
        float* rp = R + ((size_t)b * NN + r0) * 16;
#pragma unroll
        for (int reg = 0; reg < 4; reg++)
            rp[(q * 4 + reg) * 16 + m] = acc[reg];
    } else {
        // ---- column-sum path ----
        int blk2 = blk - 256;
        int b = blk2 >> 5;
        int rem = blk2 & 31;
        int jc = rem >> 4, rc = rem & 15;
        int r0 = rc * 128;
        int c0 = jc * 1024 + tid * 4;
        const float* xp = x + ((size_t)b * NN + r0) * NN + c0;

        float acc[15][4];
#pragma unroll
        for (int k = 0; k < 15; k++)
#pragma unroll
            for (int e = 0; e < 4; e++) acc[k][e] = 0.f;

        for (int rb = 0; rb < 16; rb++) {
            float4 xv[8];
#pragma unroll
            for (int q = 0; q < 8; q++)
                xv[q] = *(const float4*)(xp + (size_t)(rb * 8 + q) * NN);
#pragma unroll
            for (int q = 0; q < 8; q++) {
                int h = r0 + rb * 8 + q;
#pragma unroll
                for (int k = 0; k < 15; k++) {
                    int c = k / 3, dw = k - c * 3;
                    float wk = wr[c * (NN * 3) + h * 3 + dw];  // block-uniform -> s_load
                    acc[k][0] = fmaf(xv[q].x, wk, acc[k][0]);
                    acc[k][1] = fmaf(xv[q].y, wk, acc[k][1]);
                    acc[k][2] = fmaf(xv[q].z, wk, acc[k][2]);
                    acc[k][3] = fmaf(xv[q].w, wk, acc[k][3]);
                }
            }
        }
        float* outp = CSp + ((size_t)(rc * BB + b) * 16) * NN + c0;
#pragma unroll
        for (int k = 0; k < 15; k++) {
            float4 v; v.x = acc[k][0]; v.y = acc[k][1]; v.z = acc[k][2]; v.w = acc[k][3];
            *(float4*)(outp + (size_t)k * NN) = v;
        }
    }
}

// ---------------- k_rest: chainC (folded CSp reduce) + diag/output, one kernel ---------------
// grid 256 = 8 b x 32 tiles(64 cols == 64 diag-rows); all co-resident (1 block/CU, 27.5KB LDS).
// Phases: T-tile exp load | conv-chain on 64-col tile -> LEFT/RIGHT (agent atomics) |
//         grid barrier 1 | stage L/R slices | p + psum atomics | grid barrier 2 | output.
__global__ __launch_bounds__(256) void k_rest(const float* __restrict__ x,
                                              const float* __restrict__ R,
                                              const float* __restrict__ CSp,
                                              const float* __restrict__ bl,
                                              const float* __restrict__ br,
                                              const float* __restrict__ wA, const float* __restrict__ bA,
                                              const float* __restrict__ wB, const float* __restrict__ bB,
                                              const float* __restrict__ wT, const float* __restrict__ bT,
                                              const float* __restrict__ wm, const float* __restrict__ bm,
                                              float* __restrict__ LEFT, float* __restrict__ RIGHT,
                                              float* __restrict__ psum,
                                              int* __restrict__ counters,
                                              float* __restrict__ outp) {
    __shared__ float T[65][65];   // T[r][dm1] = exp(x[b, i0+r, i0+r+dm1+1]), +1 halo row
    __shared__ float buf0[10][80], buf1[10][80];
    __shared__ float W[3][10][10][3];
    __shared__ float Bs[3][10];
    __shared__ float Wm[2][10], Bm[2];
    __shared__ float psl[64];
    __shared__ float lfs[132], rts[68];

    int b = blockIdx.x >> 5;
    int t5 = blockIdx.x & 31;
    int c0 = t5 << 6;   // conv-chain column tile base
    int i0 = t5 << 6;   // diag i-tile base
    int tid = threadIdx.x;

    // ---- T tile (independent of conv chain; x is L3-hot from k_stage1) ----
    for (int idx = tid; idx < 65 * 64; idx += 256) {
        int r = idx >> 6, dm1 = idx & 63;
        int row = i0 + r;
        int col = row + dm1 + 1;
        float v = 0.f;
        if (row < NN && col < NN) v = __expf(x[((size_t)b * NN + row) * NN + col]);
        T[r][dm1] = v;
    }

    // ---- weights ----
    for (int idx = tid; idx < 900; idx += 256) {
        int set = idx / 300, rem = idx - set * 300;
        int o = rem / 30, rem2 = rem - o * 30, c = rem2 / 3, kk = rem2 - c * 3;
        float u;
        if (set == 0) u = wA[o * 30 + c * 3 + kk];
        else if (set == 1) u = wB[o * 30 + c * 3 + kk];
        else u = wT[c * 30 + o * 3 + (2 - kk)];   // wTc[o,c,k] = wT[c,o,2-k]
        W[set][o][c][kk] = u;
    }
    if (tid < 30) {
        float v = (tid < 10) ? bA[tid] : (tid < 20) ? bB[tid - 10] : bT[tid - 20];
        Bs[tid / 10][tid % 10] = v;
    }
    if (tid < 20) Wm[tid / 10][tid % 10] = wm[tid];
    if (tid < 2) Bm[tid] = bm[tid];

    // ---- combine: 10 ch x 76 ext positions; CS reduction over 16 rc folded in here ----
    for (int idx = tid; idx < 760; idx += 256) {
        int ch = idx / 76, p = idx - ch * 76;
        int g = c0 - 6 + p;
        float v = 0.f;
        if (g >= 0 && g < NN) {
            if (ch < 5) {
                v = bl[ch];
#pragma unroll
                for (int dh = 0; dh < 3; dh++) {
                    int r = g + dh - 1;
                    if (r >= 0 && r < NN) v += R[(size_t)(b * NN + r) * 16 + ch * 3 + dh];
                }
            } else {
                int c = ch - 5;
                v = br[c];
#pragma unroll
                for (int dw = 0; dw < 3; dw++) {
                    int j = g + dw - 1;
                    if (j >= 0 && j < NN) {
                        const float* csp = CSp + ((size_t)(b * 16) + c * 3 + dw) * NN + j;
#pragma unroll
                        for (int rc = 0; rc < 16; rc++)
                            v += csp[(size_t)rc * (8 * 16 * NN)];
                    }
                }
            }
        }
        buf0[ch][p] = v;
    }
    __syncthreads();

    // ---- 6 conv layers ----
    float(*in)[80] = buf0;
    float(*out)[80] = buf1;
    for (int layer = 0; layer < 6; layer++) {
        int set = (layer == 0) ? 0 : (layer < 3 ? 1 : 2);
        int lo = layer + 1;  // valid p range [lo, 76-lo)
        for (int idx = tid; idx < 760; idx += 256) {
            int o = idx / 76, p = idx - o * 76;
            if (p >= lo && p < 76 - lo) {
                float s = Bs[set][o];
#pragma unroll
                for (int c = 0; c < 10; c++) {
                    const float* ip = &in[c][p];
                    s = fmaf(ip[-1], W[set][o][c][0], s);
                    s = fmaf(ip[0], W[set][o][c][1], s);
                    s = fmaf(ip[1], W[set][o][c][2], s);
                }
                s = s > 0.f ? s : 0.f;
                int g = c0 - 6 + p;
                if (g < 0 || g >= NN) s = 0.f;  // reproduce zero padding at global edges
                out[o][p] = s;
            }
        }
        __syncthreads();
        float(*tmp)[80] = in; in = out; out = tmp;
    }
    // ---- 1x1 head + sigmoid; agent-scope stores so other XCDs see them after barrier ----
    if (tid < 128) {
        int o = tid >> 6, pp = tid & 63;
        int p = 6 + pp;
        float s = Bm[o];
#pragma unroll
        for (int c = 0; c < 10; c++) s = fmaf(in[c][p], Wm[o][c], s);
        float sig = 1.f / (1.f + __expf(-s));
        float* dst = (o ? RIGHT : LEFT) + b * NN + c0 + pp;
        __hip_atomic_store(dst, sig, __ATOMIC_RELAXED, __HIP_MEMORY_SCOPE_AGENT);
    }
    __syncthreads();

    // ---- grid barrier 1: LEFT/RIGHT complete ----
    if (tid == 0) {
        __threadfence();
        atomicAdd(&counters[0], 1);
        while (__hip_atomic_load(&counters[0], __ATOMIC_ACQUIRE, __HIP_MEMORY_SCOPE_AGENT) < 256) {
            __builtin_amdgcn_s_sleep(2);
        }
    }
    __syncthreads();

    // ---- stage LEFT/RIGHT slices (atomic loads bypass stale L1/L2) ----
    if (tid < 195) {
        if (tid < 129) {
            int g = i0 + 1 + tid; if (g > NN - 1) g = NN - 1;
            lfs[tid] = __hip_atomic_load(LEFT + b * NN + g, __ATOMIC_RELAXED, __HIP_MEMORY_SCOPE_AGENT);
        } else {
            int p2 = tid - 129;
            int g = i0 + p2; if (g > NN - 1) g = NN - 1;
            rts[p2] = __hip_atomic_load(RIGHT + b * NN + g, __ATOMIC_RELAXED, __HIP_MEMORY_SCOPE_AGENT);
        }
    }
    __syncthreads();

    // ---- p values + psum ----
    int wv = tid >> 6, lane = tid & 63;
    int i = i0 + lane;
    float pv[16];
#pragma unroll
    for (int s = 0; s < 16; s++) {
        int dm1 = wv * 16 + s;
        int d = dm1 + 1;
        int L = (NN - 1) - d;
        float p = 0.f;
        if (i < L) {
            float mi = T[lane + 1][dm1] * rts[lane + 1] + T[lane][dm1] * lfs[dm1 + lane];
            float mo = rts[lane] + lfs[dm1 + lane + 1];
            p = __logf(mi / mo);
        }
        pv[s] = p;
        float s64 = p;
        for (int off = 32; off; off >>= 1) s64 += __shfl_down(s64, off);
        if (lane == 0) psl[dm1] = s64;
    }
    __syncthreads();
    if (tid < 64) atomicAdd(&psum[tid], psl[tid]);
    __syncthreads();

    // ---- grid barrier 2: psum complete ----
    if (tid == 0) {
        __threadfence();
        atomicAdd(&counters[1], 1);
        while (__hip_atomic_load(&counters[1], __ATOMIC_ACQUIRE, __HIP_MEMORY_SCOPE_AGENT) < 256) {
            __builtin_amdgcn_s_sleep(2);
        }
    }
    __syncthreads();
    if (tid < 64)
        psl[tid] = __hip_atomic_load(&psum[tid], __ATOMIC_RELAXED, __HIP_MEMORY_SCOPE_AGENT);
    __syncthreads();

    // ---- output ----
#pragma unroll
    for (int s = 0; s < 16; s++) {
        int dm1 = wv * 16 + s;
        int d = dm1 + 1;
        int L = (NN - 1) - d;
        if (i < L) {
            float mean = psl[dm1] / (float)(8 * L);
            size_t off0 = (size_t)dm1 * (NN - 1) - (size_t)dm1 * (dm1 + 1) / 2;
            outp[(size_t)b * TROW + off0 + i] = pv[s] - mean;
        }
    }
}

extern "C" void kernel_launch(void* const* d_in, const int* in_sizes, int n_in,
                              void* d_out, int out_size, void* d_ws, size_t ws_size,
                              hipStream_t stream) {
    const float* x = (const float*)d_in[0];
    const float* wl = (const float*)d_in[1];
    const float* bl = (const float*)d_in[2];
    const float* wr = (const float*)d_in[3];
    const float* br = (const float*)d_in[4];
    const float* wA = (const float*)d_in[5];
    const float* bA = (const float*)d_in[6];
    const float* wB = (const float*)d_in[7];
    const float* bB = (const float*)d_in[8];
    const float* wT = (const float*)d_in[9];
    const float* bT = (const float*)d_in[10];
    const float* wm = (const float*)d_in[11];
    const float* bm = (const float*)d_in[12];

    float* ws = (float*)d_ws;
    float* R     = ws;               // 8*2048*16      = 262144 f
    float* CSp   = ws + 262144;      // 16*8*16*2048   = 4194304 f
    float* LEFT  = ws + 4456448;     // 8*2048         = 16384 f
    float* RIGHT = ws + 4472832;     // 8*2048         = 16384 f
    float* psum  = ws + 4489216;     // 64 f
    int*   counters = (int*)(ws + 4489280);  // 2 ints

    k_stage1<<<512, 256, 0, stream>>>(x, wl, wr, R, CSp, psum, counters);
    k_rest<<<256, 256, 0, stream>>>(x, R, CSp, bl, br, wA, bA, wB, bB, wT, bT, wm, bm,
                                    LEFT, RIGHT, psum, counters, (float*)d_out);
}